// Round 6
// baseline (2057.280 us; speedup 1.0000x reference)
//
#include <hip/hip_runtime.h>
#include <math.h>

#define E32   32
#define Hh    4
#define Lh    3
#define SP    15
#define SM    74
#define EPSF  1e-5f

// ---------------------------------------------------------------------------
// Setup: fuse pre_qkv (32x32) into attention in-projections.
//   qh = (x@P.T + pb)@A.T + ab  ==  x@(A@P).T + (A@pb + ab)
// 18 fused mats: [l][0..2]=self q,k,v  [l][3..5]=cross q,k,v
// ---------------------------------------------------------------------------
__global__ void fuse_weights(const float* pre_w, const float* pre_b,
                             const float* sa_inw, const float* sa_inb,
                             const float* cpre_w, const float* cpre_b,
                             const float* ca_inw, const float* ca_inb,
                             float* fw, float* fb) {
    int id = blockIdx.x;            // 0..17
    int l = id / 6, which = id % 6;
    int j = which % 3;
    bool cross = which >= 3;
    const float* A  = (cross ? ca_inw : sa_inw) + l * 96 * 32 + j * 32 * 32;
    const float* ab = (cross ? ca_inb : sa_inb) + l * 96 + j * 32;
    const float* P  = (cross ? cpre_w : pre_w) + (l * 3 + j) * 1024;
    const float* pb = (cross ? cpre_b : pre_b) + (l * 3 + j) * 32;
    float* W = fw + id * 1024;
    float* b = fb + id * 32;
    for (int i = threadIdx.x; i < 1024; i += blockDim.x) {
        int e = i >> 5, k = i & 31;
        float acc = 0.f;
        #pragma unroll
        for (int m = 0; m < 32; ++m) acc += A[e * 32 + m] * P[m * 32 + k];
        W[i] = acc;
    }
    for (int e = threadIdx.x; e < 32; e += blockDim.x) {
        float acc = ab[e];
        #pragma unroll
        for (int m = 0; m < 32; ++m) acc += A[e * 32 + m] * pb[m];
        b[e] = acc;
    }
}

// ---------------------------------------------------------------------------
// Main per-sample transformer kernel. One block (256 thr) per sample.
// NOTE: the reference overwrites x with LN(x) each time (post-LN residual
// base): x = LN(x); x = x + MHA(x); ... — so we LN in-place on xs.
// ---------------------------------------------------------------------------

// stage a 32x32 row-major W (and 32 bias) transposed into LDS: wt[k*33+e]
__device__ inline void stage32(const float* gW, const float* gB,
                               float* wt, float* bs, int t) {
    for (int i = t; i < 1024; i += 256) {
        int e = i >> 5, k = i & 31;
        wt[k * 33 + e] = gW[i];
    }
    if (t < 32) bs[t] = gB[t];
}

// out[s][e] = bias[e] + sum_k in[s*ldin+k] * wt[k*33+e], R rows
__device__ inline void mm_rows(const float* in, int ldin, int R,
                               const float* wt, const float* bs,
                               float* out, int t) {
    for (int i = t; i < R * 32; i += 256) {
        int s = i >> 5, e = i & 31;
        const float* ir = in + s * ldin;
        float acc = bs[e];
        #pragma unroll
        for (int k = 0; k < 32; ++k) acc += ir[k] * wt[k * 33 + e];
        out[s * 33 + e] = acc;
    }
}

// xs[s][e] += bias[e] + sum_k in[s*33+k] * wt[k*33+e]   (15 rows)
__device__ inline void mm_residual(const float* in, const float* wt,
                                   const float* bs, float* xs, int t) {
    for (int i = t; i < SP * 32; i += 256) {
        int s = i >> 5, e = i & 31;
        float acc = bs[e];
        #pragma unroll
        for (int k = 0; k < 32; ++k) acc += in[s * 33 + k] * wt[k * 33 + e];
        xs[s * 33 + e] += acc;
    }
}

// in-place-safe layernorm (in may == out): stats pre-sync, 1:1 writes after
__device__ inline void layernorm(const float* in, float* out,
                                 const float* g, const float* b,
                                 float* rowm, float* rowr, int t) {
    if (t < SP) {
        float m = 0.f, m2 = 0.f;
        #pragma unroll
        for (int k = 0; k < 32; ++k) {
            float v = in[t * 33 + k];
            m += v; m2 += v * v;
        }
        m *= (1.f / 32.f);
        float var = m2 * (1.f / 32.f) - m * m;
        rowm[t] = m;
        rowr[t] = rsqrtf(var + EPSF);
    }
    __syncthreads();
    for (int i = t; i < SP * 32; i += 256) {
        int s = i >> 5, e = i & 31;
        out[s * 33 + e] = (in[s * 33 + e] - rowm[s]) * rowr[s] * g[e] + b[e];
    }
}

template <int SK>
__device__ inline void attention(const float* qq, const float* kk,
                                 const float* vv, float* att, float* oo, int t) {
    // scores
    for (int i = t; i < Hh * SP * SK; i += 256) {
        int row = i / SK;          // h*SP + qi
        int kj  = i - row * SK;
        int h = row / SP, qi = row - h * SP;
        float acc = 0.f;
        #pragma unroll
        for (int d = 0; d < 8; ++d)
            acc += qq[qi * 33 + h * 8 + d] * kk[kj * 33 + h * 8 + d];
        att[row * 77 + kj] = acc * 0.35355339059327373f;   // 1/sqrt(8)
    }
    __syncthreads();
    // softmax per row (60 rows)
    for (int r = t; r < Hh * SP; r += 256) {
        float* row = att + r * 77;
        float mx = -1e30f;
        for (int j = 0; j < SK; ++j) mx = fmaxf(mx, row[j]);
        float sum = 0.f;
        for (int j = 0; j < SK; ++j) {
            float e = expf(row[j] - mx);
            row[j] = e; sum += e;
        }
        float inv = 1.f / sum;
        for (int j = 0; j < SK; ++j) row[j] *= inv;
    }
    __syncthreads();
    // PV
    for (int i = t; i < SP * 32; i += 256) {
        int s = i >> 5, c = i & 31, h = c >> 3;
        const float* row = att + (h * SP + s) * 77;
        float acc = 0.f;
        for (int j = 0; j < SK; ++j) acc += row[j] * vv[j * 33 + c];
        oo[s * 33 + c] = acc;
    }
}

__global__ __launch_bounds__(256, 2) void pan_main(
    const int* x_pep, const float* cmhc, const float* emb,
    const float* ln_g, const float* ln_b,
    const float* sa_ow, const float* sa_ob,
    const float* ca_ow, const float* ca_ob,
    const float* fc_w, const float* fc_b,
    const float* proj_w, const float* proj_b,
    const float* fw, const float* fb,
    float* t_out)
{
    const int b = blockIdx.x;
    const int t = threadIdx.x;

    __shared__ float xs[SP * 33];
    __shared__ float qq[SP * 33], kk[SP * 33], vv[SP * 33], oo[SP * 33];
    __shared__ float ck[SM * 33], cv[SM * 33];
    __shared__ float att[Hh * SP * 77];
    __shared__ float hbuf[SP * 128];
    __shared__ float wt[4224];
    __shared__ float bs[128];
    __shared__ float rowm[SP], rowr[SP];

    // --- embedding + positional encoding + tanh ---
    for (int i = t; i < SP * 32; i += 256) {
        int s = i >> 5, e = i & 31;
        int tok = x_pep[b * SP + s];
        float div = expf(-(float)(e & ~1) * 0.28782313662425572f); // ln(1e4)/32
        float ang = (float)s * div;
        float pe = (e & 1) ? cosf(ang) : sinf(ang);
        xs[s * 33 + e] = tanhf(emb[tok * 32 + e] + pe);
    }
    __syncthreads();

    const float* cm = cmhc + (size_t)b * SM * 32;

    for (int l = 0; l < Lh; ++l) {
        const float* fwl = fw + l * 6 * 1024;
        const float* fbl = fb + l * 6 * 32;

        // ---- LN1 (in-place: residual base is LN'd x) ----
        layernorm(xs, xs, ln_g + (l * 3 + 0) * 32, ln_b + (l * 3 + 0) * 32, rowm, rowr, t);
        __syncthreads();
        // ---- self-attn fused q,k,v projections (from xs) ----
        stage32(fwl + 0 * 1024, fbl + 0 * 32, wt, bs, t); __syncthreads();
        mm_rows(xs, 33, SP, wt, bs, qq, t); __syncthreads();
        stage32(fwl + 1 * 1024, fbl + 1 * 32, wt, bs, t); __syncthreads();
        mm_rows(xs, 33, SP, wt, bs, kk, t); __syncthreads();
        stage32(fwl + 2 * 1024, fbl + 2 * 32, wt, bs, t); __syncthreads();
        mm_rows(xs, 33, SP, wt, bs, vv, t); __syncthreads();
        attention<SP>(qq, kk, vv, att, oo, t); __syncthreads();
        stage32(sa_ow + l * 1024, sa_ob + l * 32, wt, bs, t); __syncthreads();
        mm_residual(oo, wt, bs, xs, t); __syncthreads();

        // ---- LN2 (in-place) ----
        layernorm(xs, xs, ln_g + (l * 3 + 1) * 32, ln_b + (l * 3 + 1) * 32, rowm, rowr, t);
        __syncthreads();
        // ---- cross-attn ----
        stage32(fwl + 3 * 1024, fbl + 3 * 32, wt, bs, t); __syncthreads();
        mm_rows(xs, 33, SP, wt, bs, qq, t); __syncthreads();
        stage32(fwl + 4 * 1024, fbl + 4 * 32, wt, bs, t); __syncthreads();
        mm_rows(cm, 32, SM, wt, bs, ck, t); __syncthreads();
        stage32(fwl + 5 * 1024, fbl + 5 * 32, wt, bs, t); __syncthreads();
        mm_rows(cm, 32, SM, wt, bs, cv, t); __syncthreads();
        attention<SM>(qq, ck, cv, att, oo, t); __syncthreads();
        stage32(ca_ow + l * 1024, ca_ob + l * 32, wt, bs, t); __syncthreads();
        mm_residual(oo, wt, bs, xs, t); __syncthreads();

        // ---- LN3 (in-place) + FFN ----
        layernorm(xs, xs, ln_g + (l * 3 + 2) * 32, ln_b + (l * 3 + 2) * 32, rowm, rowr, t);
        __syncthreads();
        // fc: [128][32] staged transposed -> wt[k*129+f]
        for (int i = t; i < 128 * 32; i += 256) {
            int f = i >> 5, k = i & 31;
            wt[k * 129 + f] = fc_w[l * 4096 + i];
        }
        if (t < 128) bs[t] = fc_b[l * 128 + t];
        __syncthreads();
        for (int i = t; i < SP * 128; i += 256) {
            int s = i >> 7, f = i & 127;
            float acc = bs[f];
            #pragma unroll
            for (int k = 0; k < 32; ++k) acc += xs[s * 33 + k] * wt[k * 129 + f];
            hbuf[s * 128 + f] = acc * 0.5f * (1.f + erff(acc * 0.70710678118654752f));
        }
        __syncthreads();
        // proj: [32][128] staged transposed -> wt[k*33+e], k<128
        for (int i = t; i < 32 * 128; i += 256) {
            int e = i >> 7, k = i & 127;
            wt[k * 33 + e] = proj_w[l * 4096 + i];
        }
        if (t < 32) bs[t] = proj_b[l * 32 + t];
        __syncthreads();
        for (int i = t; i < SP * 32; i += 256) {
            int s = i >> 5, e = i & 31;
            float acc = bs[e];
            #pragma unroll
            for (int k = 0; k < 128; ++k) acc += hbuf[s * 128 + k] * wt[k * 33 + e];
            xs[s * 33 + e] += acc;
        }
        __syncthreads();
    }

    if (t < 32) t_out[(size_t)b * 32 + t] = xs[t];   // x[:,0,:]
}

// ---------------------------------------------------------------------------
// Head kernels (batch-norm chain). 64 rows per block.
// ---------------------------------------------------------------------------
__global__ __launch_bounds__(256) void head1(const float* t_in, const float* w1,
                                             const float* b1, float* a1,
                                             double* stats, int nB) {
    __shared__ float tb[64 * 32];
    __shared__ float wtf[32 * 129];
    __shared__ float bsh[128];
    __shared__ float rs[128], rss[128];
    int t = threadIdx.x;
    int r0 = blockIdx.x * 64;
    for (int i = t; i < 64 * 32; i += 256) tb[i] = t_in[r0 * 32 + i];
    for (int i = t; i < 128 * 32; i += 256) {
        int f = i >> 5, k = i & 31;
        wtf[k * 129 + f] = w1[i];
    }
    if (t < 128) bsh[t] = b1[t];
    __syncthreads();
    int f = t & 127;
    float ls = 0.f, lss = 0.f;
    for (int rr = t >> 7; rr < 64; rr += 2) {
        float acc = bsh[f];
        #pragma unroll
        for (int k = 0; k < 32; ++k) acc += tb[rr * 32 + k] * wtf[k * 129 + f];
        acc = fmaxf(acc, 0.f);
        a1[(size_t)(r0 + rr) * 128 + f] = acc;
        ls += acc; lss += acc * acc;
    }
    if (t >= 128) { rs[f] = ls; rss[f] = lss; }
    __syncthreads();
    if (t < 128) {
        atomicAdd(&stats[f], (double)(ls + rs[f]));
        atomicAdd(&stats[128 + f], (double)(lss + rss[f]));
    }
}

__global__ __launch_bounds__(256) void head2(const float* t_in, const float* a1,
                                             const float* g, const float* bb,
                                             const float* w2, const float* b2,
                                             float* sbuf, const double* stats,
                                             double* stats2, int nB) {
    __shared__ float scale[128], shift[128];
    __shared__ float wt2[128 * 33];
    __shared__ float rs[256], rss[256];
    int t = threadIdx.x;
    if (t < 128) {
        double m = stats[t] / (double)nB;
        double var = stats[128 + t] / (double)nB - m * m;
        float sc = g[t] * rsqrtf((float)var + EPSF);
        scale[t] = sc;
        shift[t] = bb[t] - (float)m * sc;
    }
    for (int i = t; i < 32 * 128; i += 256) {
        int e = i >> 7, k = i & 127;
        wt2[k * 33 + e] = w2[i];
    }
    __syncthreads();
    int r0 = blockIdx.x * 64;
    int e = t & 31;
    float ls = 0.f, lss = 0.f;
    for (int rr = t >> 5; rr < 64; rr += 8) {
        const float* arow = a1 + (size_t)(r0 + rr) * 128;
        float acc = b2[e];
        #pragma unroll 8
        for (int k = 0; k < 128; ++k)
            acc += (arow[k] * scale[k] + shift[k]) * wt2[k * 33 + e];
        acc = fmaxf(acc, 0.f);
        float sv = t_in[(size_t)(r0 + rr) * 32 + e] + acc;
        sbuf[(size_t)(r0 + rr) * 32 + e] = sv;
        ls += sv; lss += sv * sv;
    }
    rs[t] = ls; rss[t] = lss;
    __syncthreads();
    if (t < 32) {
        float s1 = 0.f, s2 = 0.f;
        for (int j = 0; j < 8; ++j) { s1 += rs[t + 32 * j]; s2 += rss[t + 32 * j]; }
        atomicAdd(&stats2[t], (double)s1);
        atomicAdd(&stats2[32 + t], (double)s2);
    }
}

__global__ __launch_bounds__(256) void head3(const float* sbuf, const float* g,
                                             const float* bb, const float* w,
                                             const float* b, float* rbuf,
                                             const double* stats2, double* stats3,
                                             int nB) {
    __shared__ float scale[32], shift[32];
    __shared__ float wsh[8 * 32];
    __shared__ float rs[256], rss[256];
    int t = threadIdx.x;
    if (t < 32) {
        double m = stats2[t] / (double)nB;
        double var = stats2[32 + t] / (double)nB - m * m;
        float sc = g[t] * rsqrtf((float)var + EPSF);
        scale[t] = sc;
        shift[t] = bb[t] - (float)m * sc;
    }
    if (t < 8 * 32) wsh[t] = w[t];
    __syncthreads();
    int r0 = blockIdx.x * 64;
    int f = t & 7;
    float ls = 0.f, lss = 0.f;
    for (int rr = t >> 3; rr < 64; rr += 32) {
        const float* srow = sbuf + (size_t)(r0 + rr) * 32;
        float acc = b[f];
        #pragma unroll
        for (int k = 0; k < 32; ++k)
            acc += (srow[k] * scale[k] + shift[k]) * wsh[f * 32 + k];
        acc = fmaxf(acc, 0.f);
        rbuf[(size_t)(r0 + rr) * 8 + f] = acc;
        ls += acc; lss += acc * acc;
    }
    rs[t] = ls; rss[t] = lss;
    __syncthreads();
    if (t < 8) {
        float s1 = 0.f, s2 = 0.f;
        for (int j = 0; j < 32; ++j) { s1 += rs[t + 8 * j]; s2 += rss[t + 8 * j]; }
        atomicAdd(&stats3[t], (double)s1);
        atomicAdd(&stats3[8 + t], (double)s2);
    }
}

__global__ __launch_bounds__(256) void head4(const float* rbuf, const float* g,
                                             const float* bb, const float* w2,
                                             const float* b2, float* out,
                                             const double* stats3, int nB) {
    __shared__ float scale[8], shift[8], wv[8];
    int t = threadIdx.x;
    if (t < 8) {
        double m = stats3[t] / (double)nB;
        double var = stats3[8 + t] / (double)nB - m * m;
        float sc = g[t] * rsqrtf((float)var + EPSF);
        scale[t] = sc;
        shift[t] = bb[t] - (float)m * sc;
        wv[t] = w2[t];
    }
    __syncthreads();
    int i = blockIdx.x * 256 + t;
    if (i < nB) {
        const float* rr = rbuf + (size_t)i * 8;
        float acc = b2[0];
        #pragma unroll
        for (int k = 0; k < 8; ++k) acc += (rr[k] * scale[k] + shift[k]) * wv[k];
        out[i] = 1.f / (1.f + expf(-acc));
    }
}

// ---------------------------------------------------------------------------
extern "C" void kernel_launch(void* const* d_in, const int* in_sizes, int n_in,
                              void* d_out, int out_size, void* d_ws, size_t ws_size,
                              hipStream_t stream) {
    const int*   x_pep  = (const int*)  d_in[0];
    const float* cmhc   = (const float*)d_in[1];
    const float* emb    = (const float*)d_in[2];
    const float* ln_g   = (const float*)d_in[3];
    const float* ln_b   = (const float*)d_in[4];
    const float* pre_w  = (const float*)d_in[5];
    const float* pre_b  = (const float*)d_in[6];
    const float* sa_inw = (const float*)d_in[7];
    const float* sa_inb = (const float*)d_in[8];
    const float* sa_ow  = (const float*)d_in[9];
    const float* sa_ob  = (const float*)d_in[10];
    const float* cpre_w = (const float*)d_in[11];
    const float* cpre_b = (const float*)d_in[12];
    const float* ca_inw = (const float*)d_in[13];
    const float* ca_inb = (const float*)d_in[14];
    const float* ca_ow  = (const float*)d_in[15];
    const float* ca_ob  = (const float*)d_in[16];
    const float* fc_w   = (const float*)d_in[17];
    const float* fc_b   = (const float*)d_in[18];
    const float* proj_w = (const float*)d_in[19];
    const float* proj_b = (const float*)d_in[20];
    const float* h1_w1  = (const float*)d_in[21];
    const float* h1_b1  = (const float*)d_in[22];
    const float* h1_g   = (const float*)d_in[23];
    const float* h1_bb  = (const float*)d_in[24];
    const float* h1_w2  = (const float*)d_in[25];
    const float* h1_b2  = (const float*)d_in[26];
    const float* h2_g1  = (const float*)d_in[27];
    const float* h2_bb1 = (const float*)d_in[28];
    const float* h2_w1  = (const float*)d_in[29];
    const float* h2_b1  = (const float*)d_in[30];
    const float* h2_g2  = (const float*)d_in[31];
    const float* h2_bb2 = (const float*)d_in[32];
    const float* h2_w2  = (const float*)d_in[33];
    const float* h2_b2  = (const float*)d_in[34];
    float* out = (float*)d_out;

    const int nB = in_sizes[0] / SP;   // 8192

    float* wsf   = (float*)d_ws;
    float* fw    = wsf;                         // 18*1024
    float* fb    = fw + 18 * 1024;              // 18*32
    float* t_buf = fb + 18 * 32;                // nB*32
    float* a1    = t_buf + (size_t)nB * 32;     // nB*128
    float* sbuf  = a1 + (size_t)nB * 128;       // nB*32
    float* rbuf  = sbuf + (size_t)nB * 32;      // nB*8
    uintptr_t sp = (uintptr_t)(rbuf + (size_t)nB * 8);
    sp = (sp + 7) & ~(uintptr_t)7;
    double* stats  = (double*)sp;               // 128+128
    double* stats2 = stats + 256;               // 32+32
    double* stats3 = stats2 + 64;               // 8+8

    hipMemsetAsync(stats, 0, 336 * sizeof(double), stream);

    fuse_weights<<<18, 256, 0, stream>>>(pre_w, pre_b, sa_inw, sa_inb,
                                         cpre_w, cpre_b, ca_inw, ca_inb, fw, fb);

    pan_main<<<nB, 256, 0, stream>>>(x_pep, cmhc, emb, ln_g, ln_b,
                                     sa_ow, sa_ob, ca_ow, ca_ob,
                                     fc_w, fc_b, proj_w, proj_b,
                                     fw, fb, t_buf);

    head1<<<nB / 64, 256, 0, stream>>>(t_buf, h1_w1, h1_b1, a1, stats, nB);
    head2<<<nB / 64, 256, 0, stream>>>(t_buf, a1, h1_g, h1_bb, h1_w2, h1_b2,
                                       sbuf, stats, stats2, nB);
    head3<<<nB / 64, 256, 0, stream>>>(sbuf, h2_g1, h2_bb1, h2_w1, h2_b1,
                                       rbuf, stats2, stats3, nB);
    head4<<<(nB + 255) / 256, 256, 0, stream>>>(rbuf, h2_g2, h2_bb2, h2_w2, h2_b2,
                                                out, stats3, nB);
}

// Round 7
// 1448.315 us; speedup vs baseline: 1.4205x; 1.4205x over previous
//
#include <hip/hip_runtime.h>
#include <math.h>

#define E32   32
#define Hh    4
#define Lh    3
#define SP    15
#define SM    74
#define EPSF  1e-5f

// wave-synchronous fence: per-wave DS ops execute in order; this stops the
// compiler from reordering LDS accesses across phase boundaries.
#define WSYNC() do { __builtin_amdgcn_wave_barrier(); asm volatile("" ::: "memory"); } while (0)

#define XS_STRIDE 36
#define OO_STRIDE 36
#define HB_STRIDE 132
#define SAMP_LDS  2528   // 544 (xs) + 1980 (scratch) rounded; 16B-aligned

// ---------------------------------------------------------------------------
// Setup: fuse pre_qkv into attention in-projections; K-mats pre-scaled by
// 1/sqrt(8); block 18 builds the positional-encoding table.
// ---------------------------------------------------------------------------
__global__ void fuse_weights(const float* pre_w, const float* pre_b,
                             const float* sa_inw, const float* sa_inb,
                             const float* cpre_w, const float* cpre_b,
                             const float* ca_inw, const float* ca_inb,
                             float* fw, float* fb, float* pe) {
    int id = blockIdx.x;            // 0..17 weights, 18 = PE table
    if (id == 18) {
        for (int i = threadIdx.x; i < SP * 32; i += blockDim.x) {
            int s = i >> 5, e = i & 31;
            float div = expf(-(float)(e & ~1) * 0.28782313662425572f); // ln(1e4)/32
            float ang = (float)s * div;
            pe[i] = (e & 1) ? cosf(ang) : sinf(ang);
        }
        return;
    }
    int l = id / 6, which = id % 6;
    int j = which % 3;
    bool cross = which >= 3;
    float scale = (j == 1) ? 0.35355339059327373f : 1.f;   // fold 1/sqrt(Dh) into K
    const float* A  = (cross ? ca_inw : sa_inw) + l * 96 * 32 + j * 32 * 32;
    const float* ab = (cross ? ca_inb : sa_inb) + l * 96 + j * 32;
    const float* P  = (cross ? cpre_w : pre_w) + (l * 3 + j) * 1024;
    const float* pb = (cross ? cpre_b : pre_b) + (l * 3 + j) * 32;
    float* W = fw + id * 1024;
    float* b = fb + id * 32;
    for (int i = threadIdx.x; i < 1024; i += blockDim.x) {
        int e = i >> 5, k = i & 31;
        float acc = 0.f;
        #pragma unroll
        for (int m = 0; m < 32; ++m) acc += A[e * 32 + m] * P[m * 32 + k];
        W[i] = acc * scale;
    }
    for (int e = threadIdx.x; e < 32; e += blockDim.x) {
        float acc = ab[e];
        #pragma unroll
        for (int m = 0; m < 32; ++m) acc += A[e * 32 + m] * pb[m];
        b[e] = acc * scale;
    }
}

// ---------------------------------------------------------------------------
// Wave-local building blocks (one 64-lane wave owns one sample; no
// __syncthreads anywhere in pan_main).
// ---------------------------------------------------------------------------

// in-place LN: lane -> (row s = l>>2, quarter q = l&3); stats via shfl_xor.
__device__ inline void wave_ln(float* xs, const float* g, const float* bia, int l) {
    int s = l >> 2, q = l & 3;
    float v[8];
    if (s < SP) {
        const float* row = xs + s * XS_STRIDE + q * 8;
        #pragma unroll
        for (int i = 0; i < 8; ++i) v[i] = row[i];
    } else {
        #pragma unroll
        for (int i = 0; i < 8; ++i) v[i] = 0.f;
    }
    float m = 0.f, m2 = 0.f;
    #pragma unroll
    for (int i = 0; i < 8; ++i) { m += v[i]; m2 += v[i] * v[i]; }
    m += __shfl_xor(m, 1);  m2 += __shfl_xor(m2, 1);
    m += __shfl_xor(m, 2);  m2 += __shfl_xor(m2, 2);
    m *= (1.f / 32.f);
    float var = m2 * (1.f / 32.f) - m * m;
    float r = rsqrtf(var + EPSF);
    if (s < SP) {
        float* row = xs + s * XS_STRIDE + q * 8;
        #pragma unroll
        for (int i = 0; i < 8; ++i)
            row[i] = (v[i] - m) * r * g[q * 8 + i] + bia[q * 8 + i];
    }
}

// absorbed attention: lane -> (qi = l&15, h = l>>4). K/V never materialized.
// score_j = alpha + z . y_j ; o = Wv * (sum_j p_j y_j)/S + bv  (online softmax)
template <int SK>
__device__ inline void wave_attn(const float* xs, const float* xk, int ldk,
                                 const float* Wq, const float* bq,
                                 const float* Wk, const float* bk,   // pre-scaled
                                 const float* Wv, const float* bv,
                                 float* oo, int l) {
    int qi = l & 15, h = l >> 4;
    int qs = (qi < SP) ? qi : SP - 1;           // clamp inactive lanes
    const float* xq = xs + qs * XS_STRIDE;

    float q8[8];
    #pragma unroll
    for (int d = 0; d < 8; ++d) {
        const float* wr = Wq + (h * 8 + d) * 32;
        float acc = bq[h * 8 + d];
        #pragma unroll
        for (int k = 0; k < 32; ++k) acc += xq[k] * wr[k];
        q8[d] = acc;
    }
    float z[32];
    #pragma unroll
    for (int k = 0; k < 32; ++k) z[k] = 0.f;
    float alpha = 0.f;
    #pragma unroll
    for (int d = 0; d < 8; ++d) {
        const float* wr = Wk + (h * 8 + d) * 32;
        float qd = q8[d];
        alpha += qd * bk[h * 8 + d];
        #pragma unroll
        for (int k = 0; k < 32; ++k) z[k] += qd * wr[k];
    }

    float pc[32];
    #pragma unroll
    for (int k = 0; k < 32; ++k) pc[k] = 0.f;
    float M = -3.0e38f, S = 0.f;
    for (int j = 0; j < SK; ++j) {
        const float* xr = xk + j * ldk;
        float sc_ = alpha;
        #pragma unroll
        for (int k = 0; k < 32; ++k) sc_ += z[k] * xr[k];
        float t = fmaxf(M, sc_);
        float a = expf(M - t);        // 0 on first iteration (M=-3e38)
        float p = expf(sc_ - t);
        S = S * a + p;
        #pragma unroll
        for (int k = 0; k < 32; ++k) pc[k] = pc[k] * a + p * xr[k];
        M = t;
    }
    float rinv = 1.f / S;
    #pragma unroll
    for (int k = 0; k < 32; ++k) pc[k] *= rinv;

    float o8[8];
    #pragma unroll
    for (int d = 0; d < 8; ++d) {
        const float* wr = Wv + (h * 8 + d) * 32;
        float acc = bv[h * 8 + d];
        #pragma unroll
        for (int k = 0; k < 32; ++k) acc += pc[k] * wr[k];
        o8[d] = acc;
    }
    if (qi < SP) {
        float* orow = oo + qi * OO_STRIDE + h * 8;
        #pragma unroll
        for (int d = 0; d < 8; ++d) orow[d] = o8[d];
    }
}

// xs[s][e] += bo[e] + oo[s][:] . W[e][:]   lane -> (e = l&31, hi = l>>5)
__device__ inline void wave_outproj(const float* oo, const float* W, const float* bo,
                                    float* xs, int l) {
    int e = l & 31, hi = l >> 5;
    float wrow[32];
    const float* wr = W + e * 32;
    #pragma unroll
    for (int k = 0; k < 32; ++k) wrow[k] = wr[k];
    float be = bo[e];
    #pragma unroll
    for (int j = 0; j < 8; ++j) {
        int s = j * 2 + hi;
        if (s < SP) {
            const float* orow = oo + s * OO_STRIDE;
            float acc = be;
            #pragma unroll
            for (int k = 0; k < 32; ++k) acc += orow[k] * wrow[k];
            xs[s * XS_STRIDE + e] += acc;
        }
    }
}

__global__ __launch_bounds__(256, 4) void pan_main(
    const int* x_pep, const float* cmhc, const float* emb,
    const float* ln_g, const float* ln_b,
    const float* sa_ow, const float* sa_ob,
    const float* ca_ow, const float* ca_ob,
    const float* fc_w, const float* fc_b,
    const float* proj_w, const float* proj_b,
    const float* fw, const float* fb, const float* pe_tab,
    float* t_out, int nB)
{
    __shared__ float lds[4 * SAMP_LDS];
    const int w = threadIdx.x >> 6;
    const int l = threadIdx.x & 63;
    const int b = blockIdx.x * 4 + w;
    if (b >= nB) return;                     // no block-wide barriers anywhere
    float* xs = lds + w * SAMP_LDS;          // [15 x 36]
    float* sc = xs + 544;                    // scratch: oo [15x36] / hbuf [15x132]

    // embed + PE + tanh
    {
        const int* tok = x_pep + b * SP;
        #pragma unroll
        for (int j = 0; j < 8; ++j) {
            int i = j * 64 + l;
            if (i < SP * 32) {
                int s = i >> 5, e = i & 31;
                xs[s * XS_STRIDE + e] = tanhf(emb[tok[s] * 32 + e] + pe_tab[i]);
            }
        }
    }
    WSYNC();

    const float* cm = cmhc + (size_t)b * SM * 32;

    for (int ly = 0; ly < Lh; ++ly) {
        const float* fwl = fw + ly * 6 * 1024;
        const float* fbl = fb + ly * 6 * 32;

        // LN1 + self-attention + out-proj
        wave_ln(xs, ln_g + (ly * 3 + 0) * 32, ln_b + (ly * 3 + 0) * 32, l);
        WSYNC();
        wave_attn<SP>(xs, xs, XS_STRIDE,
                      fwl + 0 * 1024, fbl + 0 * 32,
                      fwl + 1 * 1024, fbl + 1 * 32,
                      fwl + 2 * 1024, fbl + 2 * 32, sc, l);
        WSYNC();
        wave_outproj(sc, sa_ow + ly * 1024, sa_ob + ly * 32, xs, l);
        WSYNC();

        // LN2 + cross-attention + out-proj
        wave_ln(xs, ln_g + (ly * 3 + 1) * 32, ln_b + (ly * 3 + 1) * 32, l);
        WSYNC();
        wave_attn<SM>(xs, cm, 32,
                      fwl + 3 * 1024, fbl + 3 * 32,
                      fwl + 4 * 1024, fbl + 4 * 32,
                      fwl + 5 * 1024, fbl + 5 * 32, sc, l);
        WSYNC();
        wave_outproj(sc, ca_ow + ly * 1024, ca_ob + ly * 32, xs, l);
        WSYNC();

        // LN3 + FFN
        wave_ln(xs, ln_g + (ly * 3 + 2) * 32, ln_b + (ly * 3 + 2) * 32, l);
        WSYNC();
        // FFN1: lane covers f = l and f = l+64
        #pragma unroll
        for (int half = 0; half < 2; ++half) {
            int f = half * 64 + l;
            const float* wr = fc_w + ly * 4096 + f * 32;
            float wrow[32];
            #pragma unroll
            for (int k = 0; k < 32; ++k) wrow[k] = wr[k];
            float bf = fc_b[ly * 128 + f];
            for (int s = 0; s < SP; ++s) {
                const float* xrow = xs + s * XS_STRIDE;
                float acc = bf;
                #pragma unroll
                for (int k = 0; k < 32; ++k) acc += xrow[k] * wrow[k];
                sc[s * HB_STRIDE + f] =
                    acc * 0.5f * (1.f + erff(acc * 0.70710678118654752f));
            }
        }
        WSYNC();
        // FFN2: lane -> (e = l&31, hi = l>>5), K chunked by 32
        {
            int e = l & 31, hi = l >> 5;
            float acc[8];
            float be = proj_b[ly * 32 + e];
            #pragma unroll
            for (int j = 0; j < 8; ++j) acc[j] = be;
            #pragma unroll
            for (int c = 0; c < 4; ++c) {
                const float* wr = proj_w + ly * 4096 + e * 128 + c * 32;
                float wrow[32];
                #pragma unroll
                for (int k = 0; k < 32; ++k) wrow[k] = wr[k];
                #pragma unroll
                for (int j = 0; j < 8; ++j) {
                    int s = j * 2 + hi;
                    if (s < SP) {
                        const float* hrow = sc + s * HB_STRIDE + c * 32;
                        #pragma unroll
                        for (int k = 0; k < 32; ++k) acc[j] += hrow[k] * wrow[k];
                    }
                }
            }
            #pragma unroll
            for (int j = 0; j < 8; ++j) {
                int s = j * 2 + hi;
                if (s < SP) xs[s * XS_STRIDE + e] += acc[j];
            }
        }
        WSYNC();
    }

    if (l < 32) t_out[(size_t)b * 32 + l] = xs[l];   // x[:,0,:]
}

// ---------------------------------------------------------------------------
// Head kernels (batch-norm chain) — unchanged.
// ---------------------------------------------------------------------------
__global__ __launch_bounds__(256) void head1(const float* t_in, const float* w1,
                                             const float* b1, float* a1,
                                             double* stats, int nB) {
    __shared__ float tb[64 * 32];
    __shared__ float wtf[32 * 129];
    __shared__ float bsh[128];
    __shared__ float rs[128], rss[128];
    int t = threadIdx.x;
    int r0 = blockIdx.x * 64;
    for (int i = t; i < 64 * 32; i += 256) tb[i] = t_in[r0 * 32 + i];
    for (int i = t; i < 128 * 32; i += 256) {
        int f = i >> 5, k = i & 31;
        wtf[k * 129 + f] = w1[i];
    }
    if (t < 128) bsh[t] = b1[t];
    __syncthreads();
    int f = t & 127;
    float ls = 0.f, lss = 0.f;
    for (int rr = t >> 7; rr < 64; rr += 2) {
        float acc = bsh[f];
        #pragma unroll
        for (int k = 0; k < 32; ++k) acc += tb[rr * 32 + k] * wtf[k * 129 + f];
        acc = fmaxf(acc, 0.f);
        a1[(size_t)(r0 + rr) * 128 + f] = acc;
        ls += acc; lss += acc * acc;
    }
    if (t >= 128) { rs[f] = ls; rss[f] = lss; }
    __syncthreads();
    if (t < 128) {
        atomicAdd(&stats[f], (double)(ls + rs[f]));
        atomicAdd(&stats[128 + f], (double)(lss + rss[f]));
    }
}

__global__ __launch_bounds__(256) void head2(const float* t_in, const float* a1,
                                             const float* g, const float* bb,
                                             const float* w2, const float* b2,
                                             float* sbuf, const double* stats,
                                             double* stats2, int nB) {
    __shared__ float scale[128], shift[128];
    __shared__ float wt2[128 * 33];
    __shared__ float rs[256], rss[256];
    int t = threadIdx.x;
    if (t < 128) {
        double m = stats[t] / (double)nB;
        double var = stats[128 + t] / (double)nB - m * m;
        float sc = g[t] * rsqrtf((float)var + EPSF);
        scale[t] = sc;
        shift[t] = bb[t] - (float)m * sc;
    }
    for (int i = t; i < 32 * 128; i += 256) {
        int e = i >> 7, k = i & 127;
        wt2[k * 33 + e] = w2[i];
    }
    __syncthreads();
    int r0 = blockIdx.x * 64;
    int e = t & 31;
    float ls = 0.f, lss = 0.f;
    for (int rr = t >> 5; rr < 64; rr += 8) {
        const float* arow = a1 + (size_t)(r0 + rr) * 128;
        float acc = b2[e];
        #pragma unroll 8
        for (int k = 0; k < 128; ++k)
            acc += (arow[k] * scale[k] + shift[k]) * wt2[k * 33 + e];
        acc = fmaxf(acc, 0.f);
        float sv = t_in[(size_t)(r0 + rr) * 32 + e] + acc;
        sbuf[(size_t)(r0 + rr) * 32 + e] = sv;
        ls += sv; lss += sv * sv;
    }
    rs[t] = ls; rss[t] = lss;
    __syncthreads();
    if (t < 32) {
        float s1 = 0.f, s2 = 0.f;
        for (int j = 0; j < 8; ++j) { s1 += rs[t + 32 * j]; s2 += rss[t + 32 * j]; }
        atomicAdd(&stats2[t], (double)s1);
        atomicAdd(&stats2[32 + t], (double)s2);
    }
}

__global__ __launch_bounds__(256) void head3(const float* sbuf, const float* g,
                                             const float* bb, const float* w,
                                             const float* b, float* rbuf,
                                             const double* stats2, double* stats3,
                                             int nB) {
    __shared__ float scale[32], shift[32];
    __shared__ float wsh[8 * 32];
    __shared__ float rs[256], rss[256];
    int t = threadIdx.x;
    if (t < 32) {
        double m = stats2[t] / (double)nB;
        double var = stats2[32 + t] / (double)nB - m * m;
        float sc = g[t] * rsqrtf((float)var + EPSF);
        scale[t] = sc;
        shift[t] = bb[t] - (float)m * sc;
    }
    if (t < 8 * 32) wsh[t] = w[t];
    __syncthreads();
    int r0 = blockIdx.x * 64;
    int f = t & 7;
    float ls = 0.f, lss = 0.f;
    for (int rr = t >> 3; rr < 64; rr += 32) {
        const float* srow = sbuf + (size_t)(r0 + rr) * 32;
        float acc = b[f];
        #pragma unroll
        for (int k = 0; k < 32; ++k)
            acc += (srow[k] * scale[k] + shift[k]) * wsh[f * 32 + k];
        acc = fmaxf(acc, 0.f);
        rbuf[(size_t)(r0 + rr) * 8 + f] = acc;
        ls += acc; lss += acc * acc;
    }
    rs[t] = ls; rss[t] = lss;
    __syncthreads();
    if (t < 8) {
        float s1 = 0.f, s2 = 0.f;
        for (int j = 0; j < 32; ++j) { s1 += rs[t + 8 * j]; s2 += rss[t + 8 * j]; }
        atomicAdd(&stats3[t], (double)s1);
        atomicAdd(&stats3[8 + t], (double)s2);
    }
}

__global__ __launch_bounds__(256) void head4(const float* rbuf, const float* g,
                                             const float* bb, const float* w2,
                                             const float* b2, float* out,
                                             const double* stats3, int nB) {
    __shared__ float scale[8], shift[8], wv[8];
    int t = threadIdx.x;
    if (t < 8) {
        double m = stats3[t] / (double)nB;
        double var = stats3[8 + t] / (double)nB - m * m;
        float sc = g[t] * rsqrtf((float)var + EPSF);
        scale[t] = sc;
        shift[t] = bb[t] - (float)m * sc;
        wv[t] = w2[t];
    }
    __syncthreads();
    int i = blockIdx.x * 256 + t;
    if (i < nB) {
        const float* rr = rbuf + (size_t)i * 8;
        float acc = b2[0];
        #pragma unroll
        for (int k = 0; k < 8; ++k) acc += (rr[k] * scale[k] + shift[k]) * wv[k];
        out[i] = 1.f / (1.f + expf(-acc));
    }
}

// ---------------------------------------------------------------------------
extern "C" void kernel_launch(void* const* d_in, const int* in_sizes, int n_in,
                              void* d_out, int out_size, void* d_ws, size_t ws_size,
                              hipStream_t stream) {
    const int*   x_pep  = (const int*)  d_in[0];
    const float* cmhc   = (const float*)d_in[1];
    const float* emb    = (const float*)d_in[2];
    const float* ln_g   = (const float*)d_in[3];
    const float* ln_b   = (const float*)d_in[4];
    const float* pre_w  = (const float*)d_in[5];
    const float* pre_b  = (const float*)d_in[6];
    const float* sa_inw = (const float*)d_in[7];
    const float* sa_inb = (const float*)d_in[8];
    const float* sa_ow  = (const float*)d_in[9];
    const float* sa_ob  = (const float*)d_in[10];
    const float* cpre_w = (const float*)d_in[11];
    const float* cpre_b = (const float*)d_in[12];
    const float* ca_inw = (const float*)d_in[13];
    const float* ca_inb = (const float*)d_in[14];
    const float* ca_ow  = (const float*)d_in[15];
    const float* ca_ob  = (const float*)d_in[16];
    const float* fc_w   = (const float*)d_in[17];
    const float* fc_b   = (const float*)d_in[18];
    const float* proj_w = (const float*)d_in[19];
    const float* proj_b = (const float*)d_in[20];
    const float* h1_w1  = (const float*)d_in[21];
    const float* h1_b1  = (const float*)d_in[22];
    const float* h1_g   = (const float*)d_in[23];
    const float* h1_bb  = (const float*)d_in[24];
    const float* h1_w2  = (const float*)d_in[25];
    const float* h1_b2  = (const float*)d_in[26];
    const float* h2_g1  = (const float*)d_in[27];
    const float* h2_bb1 = (const float*)d_in[28];
    const float* h2_w1  = (const float*)d_in[29];
    const float* h2_b1  = (const float*)d_in[30];
    const float* h2_g2  = (const float*)d_in[31];
    const float* h2_bb2 = (const float*)d_in[32];
    const float* h2_w2  = (const float*)d_in[33];
    const float* h2_b2  = (const float*)d_in[34];
    float* out = (float*)d_out;

    const int nB = in_sizes[0] / SP;   // 8192

    float* wsf   = (float*)d_ws;
    float* fw    = wsf;                         // 18*1024
    float* fb    = fw + 18 * 1024;              // 18*32
    float* pe    = fb + 18 * 32;                // 480
    float* t_buf = pe + 480;                    // nB*32
    float* a1    = t_buf + (size_t)nB * 32;     // nB*128
    float* sbuf  = a1 + (size_t)nB * 128;       // nB*32
    float* rbuf  = sbuf + (size_t)nB * 32;      // nB*8
    uintptr_t sp = (uintptr_t)(rbuf + (size_t)nB * 8);
    sp = (sp + 7) & ~(uintptr_t)7;
    double* stats  = (double*)sp;               // 128+128
    double* stats2 = stats + 256;               // 32+32
    double* stats3 = stats2 + 64;               // 8+8

    hipMemsetAsync(stats, 0, 336 * sizeof(double), stream);

    fuse_weights<<<19, 256, 0, stream>>>(pre_w, pre_b, sa_inw, sa_inb,
                                         cpre_w, cpre_b, ca_inw, ca_inb,
                                         fw, fb, pe);

    pan_main<<<(nB + 3) / 4, 256, 0, stream>>>(x_pep, cmhc, emb, ln_g, ln_b,
                                               sa_ow, sa_ob, ca_ow, ca_ob,
                                               fc_w, fc_b, proj_w, proj_b,
                                               fw, fb, pe, t_buf, nB);

    head1<<<nB / 64, 256, 0, stream>>>(t_buf, h1_w1, h1_b1, a1, stats, nB);
    head2<<<nB / 64, 256, 0, stream>>>(t_buf, a1, h1_g, h1_bb, h1_w2, h1_b2,
                                       sbuf, stats, stats2, nB);
    head3<<<nB / 64, 256, 0, stream>>>(sbuf, h2_g1, h2_bb1, h2_w1, h2_b1,
                                       rbuf, stats2, stats3, nB);
    head4<<<(nB + 255) / 256, 256, 0, stream>>>(rbuf, h2_g2, h2_bb2, h2_w2, h2_b2,
                                                out, stats3, nB);
}